// Round 3
// baseline (34539.767 us; speedup 1.0000x reference)
//
#include <hip/hip_runtime.h>

// FFJORD density on MI355X (gfx950). B=65536 rows, DIM=128, HID=512, 32 RK4 steps x 4 evals.
// Round 5: persistent per-chunk kernel. The whole RK4 chain is ROW-LOCAL, so one kernel
// (ode_k, 64 rows/block, 512 thr, 2 blocks/CU) runs all 128 evals internally:
//   Z: h1 = tanh(zs @ W1z + t*w1t + b1)  (global h1, was the separate K1 kernel)
//   A: h2 = tanh(h1 @ W2 + b2)  -> LDS panel Hs   (h1 staged via reg-preload)
//   B: f = h2 @ W3 + b3 ; accf_reg/z/zs state update  (+ g3 prefetch to regs for C)
//   C: Hs <- g2 = g3*(1-h2^2)             (in-place, prefetched g3)
//   D: Hs <- g2 @ W2^T
//   E: div = rowsum(Hs*(1-h1^2)*u) ; accd/lp in registers   (u = v@W1z per chunk)
// Launches/run: ~520 -> ~17. accf/accd/lp live in registers (thread mapping eval-invariant).
// Phase-B waves split N 8-ways (16 cols/wave): no W3 read duplication.
// Intra-block global RAW (h1, zs) is same-CU write-through + barrier-ordered; fenced.

#define DIMV 128
#define HIDV 512
#define HS_STRIDE 520  // rows 1040B: 16B-aligned for b128, 4-bank/row shift -> floor conflicts

typedef float  floatx4 __attribute__((ext_vector_type(4)));
typedef short  short8  __attribute__((ext_vector_type(8)));

static __device__ __forceinline__ unsigned short f2bf(float x) {
    union { float f; unsigned int u; } c; c.f = x;
    unsigned int u = c.u;
    u += 0x7FFFu + ((u >> 16) & 1u);   // round-to-nearest-even
    return (unsigned short)(u >> 16);
}
static __device__ __forceinline__ float bf2f(unsigned short h) {
    union { unsigned int u; float f; } c; c.u = ((unsigned int)h) << 16;
    return c.f;
}
static __device__ __forceinline__ float fast_tanh(float x) {
    x = fminf(8.0f, fmaxf(-8.0f, x));
    float e = exp2f(x * 2.8853900817779268f);            // exp(2x)
    return (e - 1.0f) * __builtin_amdgcn_rcpf(e + 1.0f); // (e-1)/(e+1)
}

// ---- weight packing: dst[(k>>3)*N*8 + n*8 + (k&7)] = bf16(W[k][n]) ------------
__global__ void pack_kernel(const float* __restrict__ src, unsigned short* __restrict__ dst,
                            int K, int N, int ld, int transpose) {
    int i = blockIdx.x * 256 + threadIdx.x;
    if (i >= K * N) return;
    int j  = i & 7;
    int n  = (i >> 3) % N;
    int k8 = (i >> 3) / N;
    int k  = k8 * 8 + j;
    float v = transpose ? src[n * ld + k] : src[k * ld + n];
    dst[i] = f2bf(v);
}

// ---- per-chunk init: z = x (fp32), zs = bf16(x) -------------------------------
__global__ void init_k(const float* __restrict__ x, float* __restrict__ z,
                       unsigned short* __restrict__ zs, int n) {
    int i = blockIdx.x * 256 + threadIdx.x;
    if (i < n) { float val = x[i]; z[i] = val; zs[i] = f2bf(val); }
}

// ---- v-GEMM producer (g3 = v@W3^T, u = v@W1z): 128 rows x 256 cols per WG -----
__global__ __launch_bounds__(256, 2) void vg_k(const float* __restrict__ v,
                                               const unsigned short* __restrict__ Wp,
                                               unsigned short* __restrict__ out0) {
    __shared__ __align__(16) unsigned short As[128 * 72];
    const int tid  = threadIdx.x;
    const int wave = tid >> 6, lane = tid & 63;
    const int quad = lane >> 4, l16 = lane & 15;
    const int row0 = blockIdx.x * 128;
    const int colw = blockIdx.y * 256 + wave * 64;

    floatx4 acc[8][4];
    #pragma unroll
    for (int m = 0; m < 8; ++m)
        #pragma unroll
        for (int f = 0; f < 4; ++f) { floatx4 zz = {0.f,0.f,0.f,0.f}; acc[m][f] = zz; }

    for (int k0 = 0; k0 < 128; k0 += 64) {
        __syncthreads();
        {
            const int r  = tid >> 3;
            const int cc = (tid & 7) << 3;
            #pragma unroll
            for (int i = 0; i < 4; ++i) {
                const int rr = r + (i << 5);
                const size_t base = (size_t)(row0 + rr) * 128 + k0 + cc;
                float vals[8];
                *(float4*)&vals[0] = *(const float4*)&v[base];
                *(float4*)&vals[4] = *(const float4*)&v[base + 4];
                short8 sv;
                #pragma unroll
                for (int j = 0; j < 8; ++j) sv[j] = (short)f2bf(vals[j]);
                *reinterpret_cast<short8*>(&As[rr * 72 + cc]) = sv;
            }
        }
        __syncthreads();
        #pragma unroll
        for (int kt = 0; kt < 2; ++kt) {
            const int k8 = (k0 >> 3) + (kt << 2) + quad;
            short8 b[4];
            #pragma unroll
            for (int f = 0; f < 4; ++f)
                b[f] = *reinterpret_cast<const short8*>(
                    &Wp[((size_t)k8 * 512 + colw + (f << 4) + l16) << 3]);
            #pragma unroll
            for (int m = 0; m < 8; ++m) {
                const short8 a = *reinterpret_cast<const short8*>(
                    &As[(m * 16 + l16) * 72 + (kt << 5) + (quad << 3)]);
                #pragma unroll
                for (int f = 0; f < 4; ++f)
                    acc[m][f] = __builtin_amdgcn_mfma_f32_16x16x32_bf16(a, b[f], acc[m][f], 0, 0, 0);
            }
        }
    }
    #pragma unroll
    for (int m = 0; m < 8; ++m)
        #pragma unroll
        for (int f = 0; f < 4; ++f) {
            const int col = colw + (f << 4) + l16;
            #pragma unroll
            for (int r = 0; r < 4; ++r) {
                const int row = row0 + m * 16 + quad * 4 + r;
                out0[(size_t)row * 512 + col] = f2bf(acc[m][f][r]);
            }
        }
}

// ---- persistent integrator ----------------------------------------------------
struct OArgs {
    const unsigned short* W1zp;  // packed (K=128,N=512)
    const unsigned short* W2p;   // packed (K=512,N=512)
    const unsigned short* W3p;   // packed (K=512,N=128)
    const unsigned short* W2Tp;  // packed (K=512,N=512)
    const unsigned short* g3;    // bf16 [C,512]
    const unsigned short* u;     // bf16 [C,512]
    const float* b1;
    const float* w1t;            // W1 row 128 (t coefficients)
    const float* b2;
    const float* b3;
    unsigned short* h1;          // bf16 [C,512] scratch
    unsigned short* zs;          // bf16 [C,128]
    float* z;                    // fp32 [C,128]
    float* lp;                   // fp32 [C]
};

__global__ __launch_bounds__(512, 4) void ode_k(OArgs p) {
    __shared__ __align__(16) unsigned short As[64 * 72];        //  9.0 KB staging
    __shared__ __align__(16) unsigned short Hs[64 * HS_STRIDE]; // 65.0 KB h2/g2/g1' panel
    const int tid  = threadIdx.x;
    const int wave = tid >> 6, lane = tid & 63;
    const int quad = lane >> 4, l16 = lane & 15;
    const int row0 = blockIdx.x * 64;
    const int colw = wave << 6;          // phases Z/A/D: 64 cols per wave
    const int sr = tid >> 3;             // streaming row 0..63
    const int sc = (tid & 7) << 3;       // streaming col-base (shorts)
    const size_t gbase = (size_t)(row0 + sr) * 512;

    const float dt = 1.0f / 32.0f;
    float accf_r[4][4];                  // RK4 f-accumulator (phase-B mapping, eval-invariant)
    float accd_r = 0.0f, lp_r = 0.0f;    // divergence accumulators (valid on tid&7==0)

    for (int e = 0; e < 128; ++e) {
        const int s = e & 3;
        const int step = e >> 2;
        const bool s0 = (s == 0), s3 = (s == 3);
        const float tph  = (s == 0) ? 0.0f : (s == 3 ? dt : 0.5f * dt);
        const float t    = (float)step * dt + tph;
        const float wrk  = (s == 1 || s == 2) ? (dt / 3.0f) : (dt / 6.0f);
        const float cnext = (s <= 1) ? 0.5f * dt : (s == 2 ? dt : 0.0f);

        // ========== phase Z: h1 = tanh(zs @ W1z + t*w1t + b1) -> global =========
        {
            floatx4 acc[4][4];
            #pragma unroll
            for (int m = 0; m < 4; ++m)
                #pragma unroll
                for (int f = 0; f < 4; ++f) { floatx4 zz = {0.f,0.f,0.f,0.f}; acc[m][f] = zz; }
            #pragma unroll
            for (int k0 = 0; k0 < 128; k0 += 64) {
                __syncthreads();   // also orders prev-eval As/Hs readers
                *reinterpret_cast<short8*>(&As[sr * 72 + sc]) =
                    *reinterpret_cast<const short8*>(&p.zs[(size_t)(row0 + sr) * 128 + k0 + sc]);
                __syncthreads();
                #pragma unroll
                for (int kt = 0; kt < 2; ++kt) {
                    const int k8 = (k0 >> 3) + (kt << 2) + quad;
                    short8 b[4];
                    #pragma unroll
                    for (int f = 0; f < 4; ++f)
                        b[f] = *reinterpret_cast<const short8*>(
                            &p.W1zp[((size_t)k8 * 512 + colw + (f << 4) + l16) << 3]);
                    #pragma unroll
                    for (int m = 0; m < 4; ++m) {
                        const short8 a = *reinterpret_cast<const short8*>(
                            &As[(m * 16 + l16) * 72 + (kt << 5) + (quad << 3)]);
                        #pragma unroll
                        for (int f = 0; f < 4; ++f)
                            acc[m][f] = __builtin_amdgcn_mfma_f32_16x16x32_bf16(a, b[f], acc[m][f], 0, 0, 0);
                    }
                }
            }
            #pragma unroll
            for (int m = 0; m < 4; ++m)
                #pragma unroll
                for (int f = 0; f < 4; ++f) {
                    const int col = colw + (f << 4) + l16;
                    const float bias = p.b1[col] + t * p.w1t[col];
                    #pragma unroll
                    for (int r = 0; r < 4; ++r) {
                        const int row = row0 + m * 16 + quad * 4 + r;
                        p.h1[(size_t)row * 512 + col] = f2bf(fast_tanh(acc[m][f][r] + bias));
                    }
                }
        }
        __threadfence_block();
        __syncthreads();   // h1 visible block-wide

        // ========== phase A: h2 = tanh(h1 @ W2 + b2) -> Hs ======================
        {
            floatx4 acc[4][4];
            #pragma unroll
            for (int m = 0; m < 4; ++m)
                #pragma unroll
                for (int f = 0; f < 4; ++f) { floatx4 zz = {0.f,0.f,0.f,0.f}; acc[m][f] = zz; }

            const unsigned short* Abase = p.h1 + gbase + sc;
            short8 st = *reinterpret_cast<const short8*>(Abase);   // k0=0 preload
            for (int k0 = 0; k0 < 512; k0 += 64) {
                __syncthreads();
                *reinterpret_cast<short8*>(&As[sr * 72 + sc]) = st;
                if (k0 + 64 < 512)
                    st = *reinterpret_cast<const short8*>(Abase + k0 + 64); // in flight
                __syncthreads();
                #pragma unroll
                for (int kt = 0; kt < 2; ++kt) {
                    const int k8 = (k0 >> 3) + (kt << 2) + quad;
                    short8 b[4];
                    #pragma unroll
                    for (int f = 0; f < 4; ++f)
                        b[f] = *reinterpret_cast<const short8*>(
                            &p.W2p[((size_t)k8 * 512 + colw + (f << 4) + l16) << 3]);
                    #pragma unroll
                    for (int m = 0; m < 4; ++m) {
                        const short8 a = *reinterpret_cast<const short8*>(
                            &As[(m * 16 + l16) * 72 + (kt << 5) + (quad << 3)]);
                        #pragma unroll
                        for (int f = 0; f < 4; ++f)
                            acc[m][f] = __builtin_amdgcn_mfma_f32_16x16x32_bf16(a, b[f], acc[m][f], 0, 0, 0);
                    }
                }
            }
            #pragma unroll
            for (int m = 0; m < 4; ++m)
                #pragma unroll
                for (int f = 0; f < 4; ++f) {
                    const int col = colw + (f << 4) + l16;
                    const float bias = p.b2[col];
                    #pragma unroll
                    for (int r = 0; r < 4; ++r) {
                        const int row = m * 16 + quad * 4 + r;
                        Hs[row * HS_STRIDE + col] = f2bf(fast_tanh(acc[m][f][r] + bias));
                    }
                }
        }
        __syncthreads();

        // ========== phase B: f = h2 @ W3 + b3 ; state update (+ g3 prefetch) ====
        short8 g3v[8];
        #pragma unroll
        for (int j = 0; j < 8; ++j)
            g3v[j] = *reinterpret_cast<const short8*>(&p.g3[gbase + sc + (j << 6)]);
        {
            floatx4 accb[4];
            #pragma unroll
            for (int m = 0; m < 4; ++m) { floatx4 zz = {0.f,0.f,0.f,0.f}; accb[m] = zz; }
            const int colB = (wave << 4) + l16;   // 16 cols per wave: no W3 duplication
            #pragma unroll 4
            for (int kt = 0; kt < 16; ++kt) {
                const int k8 = (kt << 2) + quad;
                const short8 b = *reinterpret_cast<const short8*>(
                    &p.W3p[((size_t)k8 * 128 + colB) << 3]);
                #pragma unroll
                for (int m = 0; m < 4; ++m) {
                    const short8 a = *reinterpret_cast<const short8*>(
                        &Hs[(m * 16 + l16) * HS_STRIDE + (kt << 5) + (quad << 3)]);
                    accb[m] = __builtin_amdgcn_mfma_f32_16x16x32_bf16(a, b, accb[m], 0, 0, 0);
                }
            }
            const float bias = p.b3[colB];
            #pragma unroll
            for (int m = 0; m < 4; ++m) {
                #pragma unroll
                for (int r = 0; r < 4; ++r) {
                    const int row = row0 + m * 16 + quad * 4 + r;
                    const size_t idxN = (size_t)row * 128 + colB;
                    const float x = accb[m][r] + bias;
                    const float a = wrk * x + (s0 ? 0.0f : accf_r[m][r]);
                    if (s3) {
                        const float zn = p.z[idxN] + a;     // z += dt/6 * sum(k)
                        p.z[idxN]  = zn;
                        p.zs[idxN] = f2bf(zn);              // next step s0 input
                    } else {
                        accf_r[m][r] = a;
                        p.zs[idxN]   = f2bf(p.z[idxN] + cnext * x);
                    }
                }
            }
        }
        __threadfence_block();
        __syncthreads();

        // ========== phase C: Hs <- g2 = g3 * (1 - h2^2)  (prefetched g3) ========
        #pragma unroll
        for (int j = 0; j < 8; ++j) {
            const int cc = sc + (j << 6);
            const short8 hv = *reinterpret_cast<const short8*>(&Hs[sr * HS_STRIDE + cc]);
            short8 ov;
            #pragma unroll
            for (int el = 0; el < 8; ++el) {
                const float h = bf2f((unsigned short)hv[el]);
                const float g = bf2f((unsigned short)g3v[j][el]);
                ov[el] = (short)f2bf(g * (1.0f - h * h));
            }
            *reinterpret_cast<short8*>(&Hs[sr * HS_STRIDE + cc]) = ov;
        }
        __syncthreads();

        // ========== phase D: Hs <- g2 @ W2^T ====================================
        {
            floatx4 acc[4][4];
            #pragma unroll
            for (int m = 0; m < 4; ++m)
                #pragma unroll
                for (int f = 0; f < 4; ++f) { floatx4 zz = {0.f,0.f,0.f,0.f}; acc[m][f] = zz; }
            #pragma unroll 2
            for (int kt = 0; kt < 16; ++kt) {
                const int k8 = (kt << 2) + quad;
                short8 b[4];
                #pragma unroll
                for (int f = 0; f < 4; ++f)
                    b[f] = *reinterpret_cast<const short8*>(
                        &p.W2Tp[((size_t)k8 * 512 + colw + (f << 4) + l16) << 3]);
                #pragma unroll
                for (int m = 0; m < 4; ++m) {
                    const short8 a = *reinterpret_cast<const short8*>(
                        &Hs[(m * 16 + l16) * HS_STRIDE + (kt << 5) + (quad << 3)]);
                    #pragma unroll
                    for (int f = 0; f < 4; ++f)
                        acc[m][f] = __builtin_amdgcn_mfma_f32_16x16x32_bf16(a, b[f], acc[m][f], 0, 0, 0);
                }
            }
            __syncthreads();   // all g2 reads done before in-place overwrite
            #pragma unroll
            for (int m = 0; m < 4; ++m)
                #pragma unroll
                for (int f = 0; f < 4; ++f) {
                    const int col = colw + (f << 4) + l16;
                    #pragma unroll
                    for (int r = 0; r < 4; ++r) {
                        const int row = m * 16 + quad * 4 + r;
                        Hs[row * HS_STRIDE + col] = f2bf(acc[m][f][r]);
                    }
                }
        }
        __syncthreads();

        // ========== phase E: div = rowsum(g1' * (1-h1^2) * u) ; accd/lp regs ====
        {
            float sum = 0.0f;
            short8 hv = *reinterpret_cast<const short8*>(&p.h1[gbase + sc]);
            short8 uv = *reinterpret_cast<const short8*>(&p.u[gbase + sc]);
            #pragma unroll
            for (int j = 0; j < 8; ++j) {
                short8 hvn = hv, uvn = uv;
                if (j < 7) {   // rolling 1-ahead prefetch
                    hvn = *reinterpret_cast<const short8*>(&p.h1[gbase + sc + ((j + 1) << 6)]);
                    uvn = *reinterpret_cast<const short8*>(&p.u[gbase + sc + ((j + 1) << 6)]);
                }
                const int cc = sc + (j << 6);
                const short8 xv = *reinterpret_cast<const short8*>(&Hs[sr * HS_STRIDE + cc]);
                #pragma unroll
                for (int el = 0; el < 8; ++el) {
                    const float x = bf2f((unsigned short)xv[el]);
                    const float h = bf2f((unsigned short)hv[el]);
                    const float uu = bf2f((unsigned short)uv[el]);
                    sum += x * (1.0f - h * h) * uu;
                }
                hv = hvn; uv = uvn;
            }
            sum += __shfl_xor(sum, 1);
            sum += __shfl_xor(sum, 2);
            sum += __shfl_xor(sum, 4);
            const float a = wrk * (-sum) + (s0 ? 0.0f : accd_r);
            if (s3) lp_r += a;
            else    accd_r = a;
        }
        // next eval's phase-Z first barrier orders E's Hs/h1 reads vs overwrites
    }

    if ((tid & 7) == 0) p.lp[row0 + sr] = lp_r;
}

// out[b] = lp[b] - 0.5*||z||^2 - 0.5*128*log(2*pi)
__global__ void final_k(const float* __restrict__ z, const float* __restrict__ lp,
                        float* __restrict__ out) {
    const int tid = threadIdx.x;
    const int row = blockIdx.x * 16 + (tid >> 4);
    const int l16 = tid & 15;
    const float4* zr = (const float4*)&z[(size_t)row * 128 + (l16 << 3)];
    float4 a = zr[0], b = zr[1];
    float s = a.x*a.x + a.y*a.y + a.z*a.z + a.w*a.w
            + b.x*b.x + b.y*b.y + b.z*b.z + b.w*b.w;
    s += __shfl_xor(s, 1);
    s += __shfl_xor(s, 2);
    s += __shfl_xor(s, 4);
    s += __shfl_xor(s, 8);
    if (l16 == 0) out[row] = lp[row] - 0.5f * s - 117.6241322501981f;
}

extern "C" void kernel_launch(void* const* d_in, const int* in_sizes, int n_in,
                              void* d_out, int out_size, void* d_ws, size_t ws_size,
                              hipStream_t stream) {
    (void)n_in; (void)out_size;
    const float* x  = (const float*)d_in[0];
    const float* v  = (const float*)d_in[1];
    const float* W1 = (const float*)d_in[2];
    const float* b1 = (const float*)d_in[3];
    const float* W2 = (const float*)d_in[4];
    const float* b2 = (const float*)d_in[5];
    const float* W3 = (const float*)d_in[6];
    const float* b3 = (const float*)d_in[7];
    float* out = (float*)d_out;
    const int B = in_sizes[0] / DIMV;   // 65536

    auto al = [](size_t s) { return (s + 255) & ~(size_t)255; };
    auto need_for = [&](size_t C) {
        size_t s = 0;
        s += al(C * DIMV * 4);       // z
        s += al(C * DIMV * 2);       // zs
        s += al(C * 4);              // lp
        s += al(C * HIDV * 2) * 3;   // h1, g3, u
        s += al(128 * 512 * 2) * 3 + al(512 * 512 * 2) * 2; // packed weights
        return s;
    };
    size_t C = 32768;
    while (C > 1024 && need_for(C) > ws_size) C >>= 1;
    if (need_for(C) > ws_size) return;  // cannot run safely in this workspace

    char* w = (char*)d_ws;
    auto alloc = [&](size_t bytes) { char* p = w; w += al(bytes); return p; };
    float* z    = (float*)alloc(C * DIMV * 4);
    unsigned short* zs = (unsigned short*)alloc(C * DIMV * 2);
    float* lp   = (float*)alloc(C * 4);
    unsigned short* h1 = (unsigned short*)alloc(C * HIDV * 2);
    unsigned short* g3 = (unsigned short*)alloc(C * HIDV * 2);
    unsigned short* u  = (unsigned short*)alloc(C * HIDV * 2);
    unsigned short* W1zp  = (unsigned short*)alloc(128 * 512 * 2);
    unsigned short* W3p   = (unsigned short*)alloc(512 * 128 * 2);
    unsigned short* W3Tp  = (unsigned short*)alloc(128 * 512 * 2);
    unsigned short* W2p   = (unsigned short*)alloc(512 * 512 * 2);
    unsigned short* W2Tp  = (unsigned short*)alloc(512 * 512 * 2);

    auto pack = [&](const float* src, unsigned short* dst, int K, int N, int ld, int tr) {
        pack_kernel<<<dim3((K * N + 255) / 256), dim3(256), 0, stream>>>(src, dst, K, N, ld, tr);
    };
    pack(W1, W1zp,  128, 512, 512, 0);
    pack(W2, W2p,   512, 512, 512, 0);
    pack(W3, W3p,   512, 128, 128, 0);
    pack(W2, W2Tp,  512, 512, 512, 1);
    pack(W3, W3Tp,  128, 512, 128, 1);

    const int GM128 = (int)C / 128;
    const int GMF   = (int)C / 64;

    for (int c0 = 0; c0 < B; c0 += (int)C) {
        const float* xc = x + (size_t)c0 * DIMV;
        const float* vc = v + (size_t)c0 * DIMV;

        init_k<<<dim3(((int)C * DIMV + 255) / 256), 256, 0, stream>>>(
            xc, z, zs, (int)C * DIMV);

        // g3 = v @ W3^T ; u = v @ W1z  (once per chunk)
        vg_k<<<dim3(GM128, 2), 256, 0, stream>>>(vc, W3Tp, g3);
        vg_k<<<dim3(GM128, 2), 256, 0, stream>>>(vc, W1zp, u);

        // full 32-step RK4 integration in one persistent dispatch
        OArgs q{};
        q.W1zp = W1zp; q.W2p = W2p; q.W3p = W3p; q.W2Tp = W2Tp;
        q.g3 = g3; q.u = u;
        q.b1 = b1; q.w1t = W1 + 128 * 512; q.b2 = b2; q.b3 = b3;
        q.h1 = h1; q.zs = zs; q.z = z; q.lp = lp;
        ode_k<<<dim3(GMF), 512, 0, stream>>>(q);

        final_k<<<dim3((int)C / 16), 256, 0, stream>>>(z, lp, out + c0);
    }
}

// Round 4
// 28025.830 us; speedup vs baseline: 1.2324x; 1.2324x over previous
//
#include <hip/hip_runtime.h>

// FFJORD density on MI355X (gfx950). B=65536 rows, DIM=128, HID=512, 32 RK4 steps x 4 evals.
// Round 6: zero-global-traffic integrator. Round-5 counters: hbm_bytes=37GB/dispatch @2.1TB/s
// = the whole 17.7ms (MfmaUtil 13.5%). All of it was h1 (3x/eval), g3+u (2x/eval), zs/z.
// Now: h1 and zs live in LDS panels; z/accf/accd/lp live in registers; g3/u are pinned in
// registers for the whole kernel (per-chunk constants, loaded once). Remaining traffic:
// weights from L2 (~1.3MB/block/eval, shared across blocks) + x/g3/u/z/lp once per chunk.
//   LDS: H1[64x536] 68.6K + Hs[64x536] 68.6K + Zs[64x136] 17.4K = 151KB -> 1 block/CU,
//   512 thr (8 waves), launch_bounds(512,2) -> 256-VGPR cap. 7 barriers/eval (was 22).
// Phases per eval (all operands LDS/reg): Z: h1=tanh(zs@W1z+t*w1t+b1)->H1 | A: h2=tanh(h1@W2
// +b2)->Hs | B: f=h2@W3+b3; z/accf regs; zs->Zs | C: Hs<-g3*(1-h2^2) | D: Hs<-g2@W2^T |
// E: div=rowsum(Hs*(1-h1^2)*u) -> accd/lp regs.

#define DIMV 128
#define HIDV 512
#define PAN_STR 536   // panel stride (shorts): 1072B = 67x16B aligned, 12-word bank shift/row
#define ZS_STR  136   // 272B = 17x16B aligned

typedef float  floatx4 __attribute__((ext_vector_type(4)));
typedef short  short8  __attribute__((ext_vector_type(8)));

static __device__ __forceinline__ unsigned short f2bf(float x) {
    union { float f; unsigned int u; } c; c.f = x;
    unsigned int u = c.u;
    u += 0x7FFFu + ((u >> 16) & 1u);   // round-to-nearest-even
    return (unsigned short)(u >> 16);
}
static __device__ __forceinline__ float bf2f(unsigned short h) {
    union { unsigned int u; float f; } c; c.u = ((unsigned int)h) << 16;
    return c.f;
}
static __device__ __forceinline__ float fast_tanh(float x) {
    x = fminf(8.0f, fmaxf(-8.0f, x));
    float e = exp2f(x * 2.8853900817779268f);            // exp(2x)
    return (e - 1.0f) * __builtin_amdgcn_rcpf(e + 1.0f); // (e-1)/(e+1)
}

// ---- weight packing: dst[(k>>3)*N*8 + n*8 + (k&7)] = bf16(W[k][n]) ------------
__global__ void pack_kernel(const float* __restrict__ src, unsigned short* __restrict__ dst,
                            int K, int N, int ld, int transpose) {
    int i = blockIdx.x * 256 + threadIdx.x;
    if (i >= K * N) return;
    int j  = i & 7;
    int n  = (i >> 3) % N;
    int k8 = (i >> 3) / N;
    int k  = k8 * 8 + j;
    float v = transpose ? src[n * ld + k] : src[k * ld + n];
    dst[i] = f2bf(v);
}

// ---- v-GEMM producer (g3 = v@W3^T, u = v@W1z): 128 rows x 256 cols per WG -----
__global__ __launch_bounds__(256, 2) void vg_k(const float* __restrict__ v,
                                               const unsigned short* __restrict__ Wp,
                                               unsigned short* __restrict__ out0) {
    __shared__ __align__(16) unsigned short As[128 * 72];
    const int tid  = threadIdx.x;
    const int wave = tid >> 6, lane = tid & 63;
    const int quad = lane >> 4, l16 = lane & 15;
    const int row0 = blockIdx.x * 128;
    const int colw = blockIdx.y * 256 + wave * 64;

    floatx4 acc[8][4];
    #pragma unroll
    for (int m = 0; m < 8; ++m)
        #pragma unroll
        for (int f = 0; f < 4; ++f) { floatx4 zz = {0.f,0.f,0.f,0.f}; acc[m][f] = zz; }

    for (int k0 = 0; k0 < 128; k0 += 64) {
        __syncthreads();
        {
            const int r  = tid >> 3;
            const int cc = (tid & 7) << 3;
            #pragma unroll
            for (int i = 0; i < 4; ++i) {
                const int rr = r + (i << 5);
                const size_t base = (size_t)(row0 + rr) * 128 + k0 + cc;
                float vals[8];
                *(float4*)&vals[0] = *(const float4*)&v[base];
                *(float4*)&vals[4] = *(const float4*)&v[base + 4];
                short8 sv;
                #pragma unroll
                for (int j = 0; j < 8; ++j) sv[j] = (short)f2bf(vals[j]);
                *reinterpret_cast<short8*>(&As[rr * 72 + cc]) = sv;
            }
        }
        __syncthreads();
        #pragma unroll
        for (int kt = 0; kt < 2; ++kt) {
            const int k8 = (k0 >> 3) + (kt << 2) + quad;
            short8 b[4];
            #pragma unroll
            for (int f = 0; f < 4; ++f)
                b[f] = *reinterpret_cast<const short8*>(
                    &Wp[((size_t)k8 * 512 + colw + (f << 4) + l16) << 3]);
            #pragma unroll
            for (int m = 0; m < 8; ++m) {
                const short8 a = *reinterpret_cast<const short8*>(
                    &As[(m * 16 + l16) * 72 + (kt << 5) + (quad << 3)]);
                #pragma unroll
                for (int f = 0; f < 4; ++f)
                    acc[m][f] = __builtin_amdgcn_mfma_f32_16x16x32_bf16(a, b[f], acc[m][f], 0, 0, 0);
            }
        }
    }
    #pragma unroll
    for (int m = 0; m < 8; ++m)
        #pragma unroll
        for (int f = 0; f < 4; ++f) {
            const int col = colw + (f << 4) + l16;
            #pragma unroll
            for (int r = 0; r < 4; ++r) {
                const int row = row0 + m * 16 + quad * 4 + r;
                out0[(size_t)row * 512 + col] = f2bf(acc[m][f][r]);
            }
        }
}

// ---- persistent integrator ----------------------------------------------------
struct OArgs {
    const float* x;              // fp32 input chunk [C,128]
    const unsigned short* W1zp;  // packed (K=128,N=512)
    const unsigned short* W2p;   // packed (K=512,N=512)
    const unsigned short* W3p;   // packed (K=512,N=128)
    const unsigned short* W2Tp;  // packed (K=512,N=512)
    const unsigned short* g3;    // bf16 [C,512]  (per-chunk constant)
    const unsigned short* u;     // bf16 [C,512]  (per-chunk constant)
    const float* b1;
    const float* w1t;            // W1 row 128 (t coefficients)
    const float* b2;
    const float* b3;
    float* z;                    // fp32 [C,128] out (for final_k)
    float* lp;                   // fp32 [C]
};

__global__ __launch_bounds__(512, 2) void ode_k(OArgs p) {
    __shared__ __align__(16) unsigned short H1s[64 * PAN_STR]; // 68.6 KB h1 panel
    __shared__ __align__(16) unsigned short Hss[64 * PAN_STR]; // 68.6 KB h2/g2/g1' panel
    __shared__ __align__(16) unsigned short Zss[64 * ZS_STR];  // 17.4 KB zs panel
    const int tid  = threadIdx.x;
    const int wave = tid >> 6, lane = tid & 63;
    const int quad = lane >> 4, l16 = lane & 15;
    const int row0 = blockIdx.x * 64;
    const int colw = wave << 6;          // phases Z/A/D: 64 cols per wave
    const int sr = tid >> 3;             // streaming row 0..63
    const int sc = (tid & 7) << 3;       // streaming col-base (shorts)
    const size_t gbase = (size_t)(row0 + sr) * 512;
    const int colB = (wave << 4) + l16;  // phase B column (0..127)

    // ---- per-chunk constants pinned in registers ----
    short8 g3v[8], uv[8];
    #pragma unroll
    for (int j = 0; j < 8; ++j) {
        g3v[j] = *reinterpret_cast<const short8*>(&p.g3[gbase + sc + (j << 6)]);
        uv[j]  = *reinterpret_cast<const short8*>(&p.u [gbase + sc + (j << 6)]);
    }
    float b1v[4], w1tv[4], b2v[4];
    #pragma unroll
    for (int f = 0; f < 4; ++f) {
        const int col = colw + (f << 4) + l16;
        b1v[f] = p.b1[col]; w1tv[f] = p.w1t[col]; b2v[f] = p.b2[col];
    }
    const float b3v = p.b3[colB];

    // ---- state in registers (phase-B mapping: row=m*16+quad*4+r, col=colB) ----
    float z_r[4][4];
    #pragma unroll
    for (int m = 0; m < 4; ++m)
        #pragma unroll
        for (int r = 0; r < 4; ++r) {
            const int row = m * 16 + quad * 4 + r;
            const float val = p.x[(size_t)(row0 + row) * 128 + colB];
            z_r[m][r] = val;
            Zss[row * ZS_STR + colB] = f2bf(val);
        }
    float accf_r[4][4];
    float accd_r = 0.0f, lp_r = 0.0f;    // valid on tid&7==0 lanes

    const float dt = 1.0f / 32.0f;
    floatx4 acc[4][4];                   // shared by phases Z/A/D

    for (int e = 0; e < 128; ++e) {
        const int s = e & 3;
        const int step = e >> 2;
        const bool s0 = (s == 0), s3 = (s == 3);
        const float tph  = (s == 0) ? 0.0f : (s == 3 ? dt : 0.5f * dt);
        const float t    = (float)step * dt + tph;
        const float wrk  = (s == 1 || s == 2) ? (dt / 3.0f) : (dt / 6.0f);
        const float cnext = (s <= 1) ? 0.5f * dt : (s == 2 ? dt : 0.0f);

        __syncthreads();   // (1) close prev eval: E's H1s/Hss reads done; Zss writes visible

        // ===== phase Z: h1 = tanh(zs @ W1z + t*w1t + b1) -> H1s (LDS) ==========
        #pragma unroll
        for (int m = 0; m < 4; ++m)
            #pragma unroll
            for (int f = 0; f < 4; ++f) { floatx4 zz = {0.f,0.f,0.f,0.f}; acc[m][f] = zz; }
        #pragma unroll
        for (int kt = 0; kt < 4; ++kt) {
            const int k8 = (kt << 2) + quad;
            short8 b[4];
            #pragma unroll
            for (int f = 0; f < 4; ++f)
                b[f] = *reinterpret_cast<const short8*>(
                    &p.W1zp[((size_t)k8 * 512 + colw + (f << 4) + l16) << 3]);
            #pragma unroll
            for (int m = 0; m < 4; ++m) {
                const short8 a = *reinterpret_cast<const short8*>(
                    &Zss[(m * 16 + l16) * ZS_STR + (kt << 5) + (quad << 3)]);
                #pragma unroll
                for (int f = 0; f < 4; ++f)
                    acc[m][f] = __builtin_amdgcn_mfma_f32_16x16x32_bf16(a, b[f], acc[m][f], 0, 0, 0);
            }
        }
        #pragma unroll
        for (int m = 0; m < 4; ++m)
            #pragma unroll
            for (int f = 0; f < 4; ++f) {
                const int col = colw + (f << 4) + l16;
                const float bias = b1v[f] + t * w1tv[f];
                #pragma unroll
                for (int r = 0; r < 4; ++r) {
                    const int row = m * 16 + quad * 4 + r;
                    H1s[row * PAN_STR + col] = f2bf(fast_tanh(acc[m][f][r] + bias));
                }
            }
        __syncthreads();   // (2) H1s ready

        // ===== phase A: h2 = tanh(h1 @ W2 + b2) -> Hss =========================
        #pragma unroll
        for (int m = 0; m < 4; ++m)
            #pragma unroll
            for (int f = 0; f < 4; ++f) { floatx4 zz = {0.f,0.f,0.f,0.f}; acc[m][f] = zz; }
        #pragma unroll 4
        for (int kt = 0; kt < 16; ++kt) {
            const int k8 = (kt << 2) + quad;
            short8 b[4];
            #pragma unroll
            for (int f = 0; f < 4; ++f)
                b[f] = *reinterpret_cast<const short8*>(
                    &p.W2p[((size_t)k8 * 512 + colw + (f << 4) + l16) << 3]);
            #pragma unroll
            for (int m = 0; m < 4; ++m) {
                const short8 a = *reinterpret_cast<const short8*>(
                    &H1s[(m * 16 + l16) * PAN_STR + (kt << 5) + (quad << 3)]);
                #pragma unroll
                for (int f = 0; f < 4; ++f)
                    acc[m][f] = __builtin_amdgcn_mfma_f32_16x16x32_bf16(a, b[f], acc[m][f], 0, 0, 0);
            }
        }
        #pragma unroll
        for (int m = 0; m < 4; ++m)
            #pragma unroll
            for (int f = 0; f < 4; ++f) {
                const int col = colw + (f << 4) + l16;
                #pragma unroll
                for (int r = 0; r < 4; ++r) {
                    const int row = m * 16 + quad * 4 + r;
                    Hss[row * PAN_STR + col] = f2bf(fast_tanh(acc[m][f][r] + b2v[f]));
                }
            }
        __syncthreads();   // (3) Hss (h2) ready

        // ===== phase B: f = h2 @ W3 + b3 ; z/accf regs ; zs -> Zss =============
        {
            floatx4 accb[4];
            #pragma unroll
            for (int m = 0; m < 4; ++m) { floatx4 zz = {0.f,0.f,0.f,0.f}; accb[m] = zz; }
            #pragma unroll 4
            for (int kt = 0; kt < 16; ++kt) {
                const int k8 = (kt << 2) + quad;
                const short8 b = *reinterpret_cast<const short8*>(
                    &p.W3p[((size_t)k8 * 128 + colB) << 3]);
                #pragma unroll
                for (int m = 0; m < 4; ++m) {
                    const short8 a = *reinterpret_cast<const short8*>(
                        &Hss[(m * 16 + l16) * PAN_STR + (kt << 5) + (quad << 3)]);
                    accb[m] = __builtin_amdgcn_mfma_f32_16x16x32_bf16(a, b, accb[m], 0, 0, 0);
                }
            }
            #pragma unroll
            for (int m = 0; m < 4; ++m) {
                #pragma unroll
                for (int r = 0; r < 4; ++r) {
                    const int row = m * 16 + quad * 4 + r;
                    const float x = accb[m][r] + b3v;
                    const float a = wrk * x + (s0 ? 0.0f : accf_r[m][r]);
                    if (s3) {
                        z_r[m][r] += a;                       // z += dt/6 * sum(k)
                        Zss[row * ZS_STR + colB] = f2bf(z_r[m][r]);
                    } else {
                        accf_r[m][r] = a;
                        Zss[row * ZS_STR + colB] = f2bf(z_r[m][r] + cnext * x);
                    }
                }
            }
        }
        __syncthreads();   // (4) all h2 reads done before in-place C

        // ===== phase C: Hss <- g2 = g3 * (1 - h2^2)  (pinned g3 regs) ==========
        #pragma unroll
        for (int j = 0; j < 8; ++j) {
            const int cc = sc + (j << 6);
            const short8 hv = *reinterpret_cast<const short8*>(&Hss[sr * PAN_STR + cc]);
            short8 ov;
            #pragma unroll
            for (int el = 0; el < 8; ++el) {
                const float h = bf2f((unsigned short)hv[el]);
                const float g = bf2f((unsigned short)g3v[j][el]);
                ov[el] = (short)f2bf(g * (1.0f - h * h));
            }
            *reinterpret_cast<short8*>(&Hss[sr * PAN_STR + cc]) = ov;
        }
        __syncthreads();   // (5) g2 ready

        // ===== phase D: Hss <- g2 @ W2^T ========================================
        #pragma unroll
        for (int m = 0; m < 4; ++m)
            #pragma unroll
            for (int f = 0; f < 4; ++f) { floatx4 zz = {0.f,0.f,0.f,0.f}; acc[m][f] = zz; }
        #pragma unroll 2
        for (int kt = 0; kt < 16; ++kt) {
            const int k8 = (kt << 2) + quad;
            short8 b[4];
            #pragma unroll
            for (int f = 0; f < 4; ++f)
                b[f] = *reinterpret_cast<const short8*>(
                    &p.W2Tp[((size_t)k8 * 512 + colw + (f << 4) + l16) << 3]);
            #pragma unroll
            for (int m = 0; m < 4; ++m) {
                const short8 a = *reinterpret_cast<const short8*>(
                    &Hss[(m * 16 + l16) * PAN_STR + (kt << 5) + (quad << 3)]);
                #pragma unroll
                for (int f = 0; f < 4; ++f)
                    acc[m][f] = __builtin_amdgcn_mfma_f32_16x16x32_bf16(a, b[f], acc[m][f], 0, 0, 0);
            }
        }
        __syncthreads();   // (6) all g2 reads done before overwrite
        #pragma unroll
        for (int m = 0; m < 4; ++m)
            #pragma unroll
            for (int f = 0; f < 4; ++f) {
                const int col = colw + (f << 4) + l16;
                #pragma unroll
                for (int r = 0; r < 4; ++r) {
                    const int row = m * 16 + quad * 4 + r;
                    Hss[row * PAN_STR + col] = f2bf(acc[m][f][r]);
                }
            }
        __syncthreads();   // (7) g1' ready

        // ===== phase E: div = rowsum(g1' * (1-h1^2) * u) ; accd/lp regs ========
        {
            float sum = 0.0f;
            #pragma unroll
            for (int j = 0; j < 8; ++j) {
                const int cc = sc + (j << 6);
                const short8 xv = *reinterpret_cast<const short8*>(&Hss[sr * PAN_STR + cc]);
                const short8 hv = *reinterpret_cast<const short8*>(&H1s[sr * PAN_STR + cc]);
                #pragma unroll
                for (int el = 0; el < 8; ++el) {
                    const float x = bf2f((unsigned short)xv[el]);
                    const float h = bf2f((unsigned short)hv[el]);
                    const float uu = bf2f((unsigned short)uv[j][el]);
                    sum += x * (1.0f - h * h) * uu;
                }
            }
            sum += __shfl_xor(sum, 1);
            sum += __shfl_xor(sum, 2);
            sum += __shfl_xor(sum, 4);
            const float a = wrk * (-sum) + (s0 ? 0.0f : accd_r);
            if (s3) lp_r += a;
            else    accd_r = a;
        }
        // next eval's barrier (1) orders E's H1s/Hss reads vs Z's overwrites
    }

    // ---- write final state ----
    #pragma unroll
    for (int m = 0; m < 4; ++m)
        #pragma unroll
        for (int r = 0; r < 4; ++r)
            p.z[(size_t)(row0 + m * 16 + quad * 4 + r) * 128 + colB] = z_r[m][r];
    if ((tid & 7) == 0) p.lp[row0 + sr] = lp_r;
}

// out[b] = lp[b] - 0.5*||z||^2 - 0.5*128*log(2*pi)
__global__ void final_k(const float* __restrict__ z, const float* __restrict__ lp,
                        float* __restrict__ out) {
    const int tid = threadIdx.x;
    const int row = blockIdx.x * 16 + (tid >> 4);
    const int l16 = tid & 15;
    const float4* zr = (const float4*)&z[(size_t)row * 128 + (l16 << 3)];
    float4 a = zr[0], b = zr[1];
    float s = a.x*a.x + a.y*a.y + a.z*a.z + a.w*a.w
            + b.x*b.x + b.y*b.y + b.z*b.z + b.w*b.w;
    s += __shfl_xor(s, 1);
    s += __shfl_xor(s, 2);
    s += __shfl_xor(s, 4);
    s += __shfl_xor(s, 8);
    if (l16 == 0) out[row] = lp[row] - 0.5f * s - 117.6241322501981f;
}

extern "C" void kernel_launch(void* const* d_in, const int* in_sizes, int n_in,
                              void* d_out, int out_size, void* d_ws, size_t ws_size,
                              hipStream_t stream) {
    (void)n_in; (void)out_size;
    const float* x  = (const float*)d_in[0];
    const float* v  = (const float*)d_in[1];
    const float* W1 = (const float*)d_in[2];
    const float* b1 = (const float*)d_in[3];
    const float* W2 = (const float*)d_in[4];
    const float* b2 = (const float*)d_in[5];
    const float* W3 = (const float*)d_in[6];
    const float* b3 = (const float*)d_in[7];
    float* out = (float*)d_out;
    const int B = in_sizes[0] / DIMV;   // 65536

    auto al = [](size_t s) { return (s + 255) & ~(size_t)255; };
    auto need_for = [&](size_t C) {
        size_t s = 0;
        s += al(C * DIMV * 4);       // z
        s += al(C * 4);              // lp
        s += al(C * HIDV * 2) * 2;   // g3, u
        s += al(128 * 512 * 2) * 3 + al(512 * 512 * 2) * 2; // packed weights
        return s;
    };
    size_t C = 32768;
    while (C > 1024 && need_for(C) > ws_size) C >>= 1;
    if (need_for(C) > ws_size) return;  // cannot run safely in this workspace

    char* w = (char*)d_ws;
    auto alloc = [&](size_t bytes) { char* p = w; w += al(bytes); return p; };
    float* z    = (float*)alloc(C * DIMV * 4);
    float* lp   = (float*)alloc(C * 4);
    unsigned short* g3 = (unsigned short*)alloc(C * HIDV * 2);
    unsigned short* u  = (unsigned short*)alloc(C * HIDV * 2);
    unsigned short* W1zp  = (unsigned short*)alloc(128 * 512 * 2);
    unsigned short* W3p   = (unsigned short*)alloc(512 * 128 * 2);
    unsigned short* W3Tp  = (unsigned short*)alloc(128 * 512 * 2);
    unsigned short* W2p   = (unsigned short*)alloc(512 * 512 * 2);
    unsigned short* W2Tp  = (unsigned short*)alloc(512 * 512 * 2);

    auto pack = [&](const float* src, unsigned short* dst, int K, int N, int ld, int tr) {
        pack_kernel<<<dim3((K * N + 255) / 256), dim3(256), 0, stream>>>(src, dst, K, N, ld, tr);
    };
    pack(W1, W1zp,  128, 512, 512, 0);
    pack(W2, W2p,   512, 512, 512, 0);
    pack(W3, W3p,   512, 128, 128, 0);
    pack(W2, W2Tp,  512, 512, 512, 1);
    pack(W3, W3Tp,  128, 512, 128, 1);

    const int GM128 = (int)C / 128;
    const int GMF   = (int)C / 64;

    for (int c0 = 0; c0 < B; c0 += (int)C) {
        const float* xc = x + (size_t)c0 * DIMV;
        const float* vc = v + (size_t)c0 * DIMV;

        // g3 = v @ W3^T ; u = v @ W1z  (once per chunk)
        vg_k<<<dim3(GM128, 2), 256, 0, stream>>>(vc, W3Tp, g3);
        vg_k<<<dim3(GM128, 2), 256, 0, stream>>>(vc, W1zp, u);

        // full 32-step RK4 integration in one persistent dispatch
        OArgs q{};
        q.x = xc;
        q.W1zp = W1zp; q.W2p = W2p; q.W3p = W3p; q.W2Tp = W2Tp;
        q.g3 = g3; q.u = u;
        q.b1 = b1; q.w1t = W1 + 128 * 512; q.b2 = b2; q.b3 = b3;
        q.z = z; q.lp = lp;
        ode_k<<<dim3(GMF), 512, 0, stream>>>(q);

        final_k<<<dim3((int)C / 16), 256, 0, stream>>>(z, lp, out + c0);
    }
}

// Round 5
// 25082.310 us; speedup vs baseline: 1.3771x; 1.1174x over previous
//
#include <hip/hip_runtime.h>

// FFJORD density on MI355X (gfx950). B=65536 rows, DIM=128, HID=512, 32 RK4 steps x 4 evals.
// Round 7: restore 2 blocks/CU. Round-6 counters: traffic fixed (HBM 3-8%) but LDS 154.6KB
// -> 1 block/CU, occupancy 23.7%, MfmaUtil 15% = latency-bound with no cross-phase overlap.
// Now 32-row blocks: LDS = H1[32x536] + Hs[32x536] + Zs[32x136] = 75.5KB -> 2 blocks/CU,
// 4 waves/SIMD, launch_bounds(512,4) (128-VGPR cap; 32-row tiling needs ~112 regs).
// Two co-resident blocks run phase-shifted: one block's MFMA hides the other's barriers.
// Phase structure unchanged from round 6 (zero state traffic, weights from L2):
//   Z: h1=tanh(zs@W1z+t*w1t+b1)->H1 | A: h2=tanh(h1@W2+b2)->Hs | B: f=h2@W3+b3, z/accf regs,
//   zs->Zs | C: Hs<-g3*(1-h2^2) | D: Hs<-g2@W2^T | E: div=rowsum(Hs*(1-h1^2)*u)->accd/lp regs.

#define DIMV 128
#define HIDV 512
#define ROWS 32
#define PAN_STR 536   // panel stride (shorts): 1072B, 16B-aligned, 12-word bank shift/row
#define ZS_STR  136   // 272B, 16B-aligned

typedef float  floatx4 __attribute__((ext_vector_type(4)));
typedef short  short8  __attribute__((ext_vector_type(8)));

static __device__ __forceinline__ unsigned short f2bf(float x) {
    union { float f; unsigned int u; } c; c.f = x;
    unsigned int u = c.u;
    u += 0x7FFFu + ((u >> 16) & 1u);   // round-to-nearest-even
    return (unsigned short)(u >> 16);
}
static __device__ __forceinline__ float bf2f(unsigned short h) {
    union { unsigned int u; float f; } c; c.u = ((unsigned int)h) << 16;
    return c.f;
}
static __device__ __forceinline__ float fast_tanh(float x) {
    x = fminf(8.0f, fmaxf(-8.0f, x));
    float e = exp2f(x * 2.8853900817779268f);            // exp(2x)
    return (e - 1.0f) * __builtin_amdgcn_rcpf(e + 1.0f); // (e-1)/(e+1)
}

// ---- weight packing: dst[(k>>3)*N*8 + n*8 + (k&7)] = bf16(W[k][n]) ------------
__global__ void pack_kernel(const float* __restrict__ src, unsigned short* __restrict__ dst,
                            int K, int N, int ld, int transpose) {
    int i = blockIdx.x * 256 + threadIdx.x;
    if (i >= K * N) return;
    int j  = i & 7;
    int n  = (i >> 3) % N;
    int k8 = (i >> 3) / N;
    int k  = k8 * 8 + j;
    float v = transpose ? src[n * ld + k] : src[k * ld + n];
    dst[i] = f2bf(v);
}

// ---- v-GEMM producer (g3 = v@W3^T, u = v@W1z): 128 rows x 256 cols per WG -----
__global__ __launch_bounds__(256, 2) void vg_k(const float* __restrict__ v,
                                               const unsigned short* __restrict__ Wp,
                                               unsigned short* __restrict__ out0) {
    __shared__ __align__(16) unsigned short As[128 * 72];
    const int tid  = threadIdx.x;
    const int wave = tid >> 6, lane = tid & 63;
    const int quad = lane >> 4, l16 = lane & 15;
    const int row0 = blockIdx.x * 128;
    const int colw = blockIdx.y * 256 + wave * 64;

    floatx4 acc[8][4];
    #pragma unroll
    for (int m = 0; m < 8; ++m)
        #pragma unroll
        for (int f = 0; f < 4; ++f) { floatx4 zz = {0.f,0.f,0.f,0.f}; acc[m][f] = zz; }

    for (int k0 = 0; k0 < 128; k0 += 64) {
        __syncthreads();
        {
            const int r  = tid >> 3;
            const int cc = (tid & 7) << 3;
            #pragma unroll
            for (int i = 0; i < 4; ++i) {
                const int rr = r + (i << 5);
                const size_t base = (size_t)(row0 + rr) * 128 + k0 + cc;
                float vals[8];
                *(float4*)&vals[0] = *(const float4*)&v[base];
                *(float4*)&vals[4] = *(const float4*)&v[base + 4];
                short8 sv;
                #pragma unroll
                for (int j = 0; j < 8; ++j) sv[j] = (short)f2bf(vals[j]);
                *reinterpret_cast<short8*>(&As[rr * 72 + cc]) = sv;
            }
        }
        __syncthreads();
        #pragma unroll
        for (int kt = 0; kt < 2; ++kt) {
            const int k8 = (k0 >> 3) + (kt << 2) + quad;
            short8 b[4];
            #pragma unroll
            for (int f = 0; f < 4; ++f)
                b[f] = *reinterpret_cast<const short8*>(
                    &Wp[((size_t)k8 * 512 + colw + (f << 4) + l16) << 3]);
            #pragma unroll
            for (int m = 0; m < 8; ++m) {
                const short8 a = *reinterpret_cast<const short8*>(
                    &As[(m * 16 + l16) * 72 + (kt << 5) + (quad << 3)]);
                #pragma unroll
                for (int f = 0; f < 4; ++f)
                    acc[m][f] = __builtin_amdgcn_mfma_f32_16x16x32_bf16(a, b[f], acc[m][f], 0, 0, 0);
            }
        }
    }
    #pragma unroll
    for (int m = 0; m < 8; ++m)
        #pragma unroll
        for (int f = 0; f < 4; ++f) {
            const int col = colw + (f << 4) + l16;
            #pragma unroll
            for (int r = 0; r < 4; ++r) {
                const int row = row0 + m * 16 + quad * 4 + r;
                out0[(size_t)row * 512 + col] = f2bf(acc[m][f][r]);
            }
        }
}

// ---- persistent integrator ----------------------------------------------------
struct OArgs {
    const float* x;              // fp32 input chunk [C,128]
    const unsigned short* W1zp;  // packed (K=128,N=512)
    const unsigned short* W2p;   // packed (K=512,N=512)
    const unsigned short* W3p;   // packed (K=512,N=128)
    const unsigned short* W2Tp;  // packed (K=512,N=512)
    const unsigned short* g3;    // bf16 [C,512]  (per-chunk constant)
    const unsigned short* u;     // bf16 [C,512]  (per-chunk constant)
    const float* b1;
    const float* w1t;            // W1 row 128 (t coefficients)
    const float* b2;
    const float* b3;
    float* z;                    // fp32 [C,128] out (for final_k)
    float* lp;                   // fp32 [C]
};

__global__ __launch_bounds__(512, 4) void ode_k(OArgs p) {
    __shared__ __align__(16) unsigned short H1s[ROWS * PAN_STR]; // 34.3 KB h1 panel
    __shared__ __align__(16) unsigned short Hss[ROWS * PAN_STR]; // 34.3 KB h2/g2/g1' panel
    __shared__ __align__(16) unsigned short Zss[ROWS * ZS_STR];  //  8.7 KB zs panel
    const int tid  = threadIdx.x;
    const int wave = tid >> 6, lane = tid & 63;
    const int quad = lane >> 4, l16 = lane & 15;
    const int row0 = blockIdx.x * ROWS;
    const int colw = wave << 6;          // phases Z/A/D: 64 cols per wave
    const int sr = tid >> 4;             // streaming row 0..31 (16 threads/row)
    const int sc = (tid & 15) << 3;      // streaming col-base (shorts), 128 cols/pass
    const size_t gbase = (size_t)(row0 + sr) * 512;
    const int colB = (wave << 4) + l16;  // phase B column (0..127)

    // ---- per-chunk constants pinned in registers (streaming mapping) ----
    short8 g3v[4], uv[4];
    #pragma unroll
    for (int j = 0; j < 4; ++j) {
        g3v[j] = *reinterpret_cast<const short8*>(&p.g3[gbase + sc + (j << 7)]);
        uv[j]  = *reinterpret_cast<const short8*>(&p.u [gbase + sc + (j << 7)]);
    }
    float b1v[4], w1tv[4], b2v[4];
    #pragma unroll
    for (int f = 0; f < 4; ++f) {
        const int col = colw + (f << 4) + l16;
        b1v[f] = p.b1[col]; w1tv[f] = p.w1t[col]; b2v[f] = p.b2[col];
    }
    const float b3v = p.b3[colB];

    // ---- state in registers (phase-B mapping: row=m*16+quad*4+r, col=colB) ----
    float z_r[2][4];
    #pragma unroll
    for (int m = 0; m < 2; ++m)
        #pragma unroll
        for (int r = 0; r < 4; ++r) {
            const int row = m * 16 + quad * 4 + r;
            const float val = p.x[(size_t)(row0 + row) * 128 + colB];
            z_r[m][r] = val;
            Zss[row * ZS_STR + colB] = f2bf(val);
        }
    float accf_r[2][4];
    float accd_r = 0.0f, lp_r = 0.0f;    // valid on tid&15==0 lanes

    const float dt = 1.0f / 32.0f;
    floatx4 acc[2][4];                   // shared by phases Z/A/D

    for (int e = 0; e < 128; ++e) {
        const int s = e & 3;
        const int step = e >> 2;
        const bool s0 = (s == 0), s3 = (s == 3);
        const float tph  = (s == 0) ? 0.0f : (s == 3 ? dt : 0.5f * dt);
        const float t    = (float)step * dt + tph;
        const float wrk  = (s == 1 || s == 2) ? (dt / 3.0f) : (dt / 6.0f);
        const float cnext = (s <= 1) ? 0.5f * dt : (s == 2 ? dt : 0.0f);

        __syncthreads();   // (1) close prev eval: E's H1s/Hss reads done; Zss writes visible

        // ===== phase Z: h1 = tanh(zs @ W1z + t*w1t + b1) -> H1s ================
        #pragma unroll
        for (int m = 0; m < 2; ++m)
            #pragma unroll
            for (int f = 0; f < 4; ++f) { floatx4 zz = {0.f,0.f,0.f,0.f}; acc[m][f] = zz; }
        #pragma unroll
        for (int kt = 0; kt < 4; ++kt) {
            const int k8 = (kt << 2) + quad;
            short8 b[4];
            #pragma unroll
            for (int f = 0; f < 4; ++f)
                b[f] = *reinterpret_cast<const short8*>(
                    &p.W1zp[((size_t)k8 * 512 + colw + (f << 4) + l16) << 3]);
            #pragma unroll
            for (int m = 0; m < 2; ++m) {
                const short8 a = *reinterpret_cast<const short8*>(
                    &Zss[(m * 16 + l16) * ZS_STR + (kt << 5) + (quad << 3)]);
                #pragma unroll
                for (int f = 0; f < 4; ++f)
                    acc[m][f] = __builtin_amdgcn_mfma_f32_16x16x32_bf16(a, b[f], acc[m][f], 0, 0, 0);
            }
        }
        #pragma unroll
        for (int m = 0; m < 2; ++m)
            #pragma unroll
            for (int f = 0; f < 4; ++f) {
                const int col = colw + (f << 4) + l16;
                const float bias = b1v[f] + t * w1tv[f];
                #pragma unroll
                for (int r = 0; r < 4; ++r) {
                    const int row = m * 16 + quad * 4 + r;
                    H1s[row * PAN_STR + col] = f2bf(fast_tanh(acc[m][f][r] + bias));
                }
            }
        __syncthreads();   // (2) H1s ready

        // ===== phase A: h2 = tanh(h1 @ W2 + b2) -> Hss =========================
        #pragma unroll
        for (int m = 0; m < 2; ++m)
            #pragma unroll
            for (int f = 0; f < 4; ++f) { floatx4 zz = {0.f,0.f,0.f,0.f}; acc[m][f] = zz; }
        #pragma unroll 4
        for (int kt = 0; kt < 16; ++kt) {
            const int k8 = (kt << 2) + quad;
            short8 b[4];
            #pragma unroll
            for (int f = 0; f < 4; ++f)
                b[f] = *reinterpret_cast<const short8*>(
                    &p.W2p[((size_t)k8 * 512 + colw + (f << 4) + l16) << 3]);
            #pragma unroll
            for (int m = 0; m < 2; ++m) {
                const short8 a = *reinterpret_cast<const short8*>(
                    &H1s[(m * 16 + l16) * PAN_STR + (kt << 5) + (quad << 3)]);
                #pragma unroll
                for (int f = 0; f < 4; ++f)
                    acc[m][f] = __builtin_amdgcn_mfma_f32_16x16x32_bf16(a, b[f], acc[m][f], 0, 0, 0);
            }
        }
        #pragma unroll
        for (int m = 0; m < 2; ++m)
            #pragma unroll
            for (int f = 0; f < 4; ++f) {
                const int col = colw + (f << 4) + l16;
                #pragma unroll
                for (int r = 0; r < 4; ++r) {
                    const int row = m * 16 + quad * 4 + r;
                    Hss[row * PAN_STR + col] = f2bf(fast_tanh(acc[m][f][r] + b2v[f]));
                }
            }
        __syncthreads();   // (3) Hss (h2) ready

        // ===== phase B: f = h2 @ W3 + b3 ; z/accf regs ; zs -> Zss =============
        {
            floatx4 accb[2];
            #pragma unroll
            for (int m = 0; m < 2; ++m) { floatx4 zz = {0.f,0.f,0.f,0.f}; accb[m] = zz; }
            #pragma unroll 4
            for (int kt = 0; kt < 16; ++kt) {
                const int k8 = (kt << 2) + quad;
                const short8 b = *reinterpret_cast<const short8*>(
                    &p.W3p[((size_t)k8 * 128 + colB) << 3]);
                #pragma unroll
                for (int m = 0; m < 2; ++m) {
                    const short8 a = *reinterpret_cast<const short8*>(
                        &Hss[(m * 16 + l16) * PAN_STR + (kt << 5) + (quad << 3)]);
                    accb[m] = __builtin_amdgcn_mfma_f32_16x16x32_bf16(a, b, accb[m], 0, 0, 0);
                }
            }
            #pragma unroll
            for (int m = 0; m < 2; ++m) {
                #pragma unroll
                for (int r = 0; r < 4; ++r) {
                    const int row = m * 16 + quad * 4 + r;
                    const float x = accb[m][r] + b3v;
                    const float a = wrk * x + (s0 ? 0.0f : accf_r[m][r]);
                    if (s3) {
                        z_r[m][r] += a;                       // z += dt/6 * sum(k)
                        Zss[row * ZS_STR + colB] = f2bf(z_r[m][r]);
                    } else {
                        accf_r[m][r] = a;
                        Zss[row * ZS_STR + colB] = f2bf(z_r[m][r] + cnext * x);
                    }
                }
            }
        }
        __syncthreads();   // (4) all h2 reads done before in-place C

        // ===== phase C: Hss <- g2 = g3 * (1 - h2^2)  (pinned g3 regs) ==========
        #pragma unroll
        for (int j = 0; j < 4; ++j) {
            const int cc = sc + (j << 7);
            const short8 hv = *reinterpret_cast<const short8*>(&Hss[sr * PAN_STR + cc]);
            short8 ov;
            #pragma unroll
            for (int el = 0; el < 8; ++el) {
                const float h = bf2f((unsigned short)hv[el]);
                const float g = bf2f((unsigned short)g3v[j][el]);
                ov[el] = (short)f2bf(g * (1.0f - h * h));
            }
            *reinterpret_cast<short8*>(&Hss[sr * PAN_STR + cc]) = ov;
        }
        __syncthreads();   // (5) g2 ready

        // ===== phase D: Hss <- g2 @ W2^T ========================================
        #pragma unroll
        for (int m = 0; m < 2; ++m)
            #pragma unroll
            for (int f = 0; f < 4; ++f) { floatx4 zz = {0.f,0.f,0.f,0.f}; acc[m][f] = zz; }
        #pragma unroll 4
        for (int kt = 0; kt < 16; ++kt) {
            const int k8 = (kt << 2) + quad;
            short8 b[4];
            #pragma unroll
            for (int f = 0; f < 4; ++f)
                b[f] = *reinterpret_cast<const short8*>(
                    &p.W2Tp[((size_t)k8 * 512 + colw + (f << 4) + l16) << 3]);
            #pragma unroll
            for (int m = 0; m < 2; ++m) {
                const short8 a = *reinterpret_cast<const short8*>(
                    &Hss[(m * 16 + l16) * PAN_STR + (kt << 5) + (quad << 3)]);
                #pragma unroll
                for (int f = 0; f < 4; ++f)
                    acc[m][f] = __builtin_amdgcn_mfma_f32_16x16x32_bf16(a, b[f], acc[m][f], 0, 0, 0);
            }
        }
        __syncthreads();   // (6) all g2 reads done before overwrite
        #pragma unroll
        for (int m = 0; m < 2; ++m)
            #pragma unroll
            for (int f = 0; f < 4; ++f) {
                const int col = colw + (f << 4) + l16;
                #pragma unroll
                for (int r = 0; r < 4; ++r) {
                    const int row = m * 16 + quad * 4 + r;
                    Hss[row * PAN_STR + col] = f2bf(acc[m][f][r]);
                }
            }
        __syncthreads();   // (7) g1' ready

        // ===== phase E: div = rowsum(g1' * (1-h1^2) * u) ; accd/lp regs ========
        {
            float sum = 0.0f;
            #pragma unroll
            for (int j = 0; j < 4; ++j) {
                const int cc = sc + (j << 7);
                const short8 xv = *reinterpret_cast<const short8*>(&Hss[sr * PAN_STR + cc]);
                const short8 hv = *reinterpret_cast<const short8*>(&H1s[sr * PAN_STR + cc]);
                #pragma unroll
                for (int el = 0; el < 8; ++el) {
                    const float x = bf2f((unsigned short)xv[el]);
                    const float h = bf2f((unsigned short)hv[el]);
                    const float uu = bf2f((unsigned short)uv[j][el]);
                    sum += x * (1.0f - h * h) * uu;
                }
            }
            sum += __shfl_xor(sum, 1);
            sum += __shfl_xor(sum, 2);
            sum += __shfl_xor(sum, 4);
            sum += __shfl_xor(sum, 8);
            const float a = wrk * (-sum) + (s0 ? 0.0f : accd_r);
            if (s3) lp_r += a;
            else    accd_r = a;
        }
        // next eval's barrier (1) orders E's H1s/Hss reads vs Z's overwrites
    }

    // ---- write final state ----
    #pragma unroll
    for (int m = 0; m < 2; ++m)
        #pragma unroll
        for (int r = 0; r < 4; ++r)
            p.z[(size_t)(row0 + m * 16 + quad * 4 + r) * 128 + colB] = z_r[m][r];
    if ((tid & 15) == 0) p.lp[row0 + sr] = lp_r;
}

// out[b] = lp[b] - 0.5*||z||^2 - 0.5*128*log(2*pi)
__global__ void final_k(const float* __restrict__ z, const float* __restrict__ lp,
                        float* __restrict__ out) {
    const int tid = threadIdx.x;
    const int row = blockIdx.x * 16 + (tid >> 4);
    const int l16 = tid & 15;
    const float4* zr = (const float4*)&z[(size_t)row * 128 + (l16 << 3)];
    float4 a = zr[0], b = zr[1];
    float s = a.x*a.x + a.y*a.y + a.z*a.z + a.w*a.w
            + b.x*b.x + b.y*b.y + b.z*b.z + b.w*b.w;
    s += __shfl_xor(s, 1);
    s += __shfl_xor(s, 2);
    s += __shfl_xor(s, 4);
    s += __shfl_xor(s, 8);
    if (l16 == 0) out[row] = lp[row] - 0.5f * s - 117.6241322501981f;
}

extern "C" void kernel_launch(void* const* d_in, const int* in_sizes, int n_in,
                              void* d_out, int out_size, void* d_ws, size_t ws_size,
                              hipStream_t stream) {
    (void)n_in; (void)out_size;
    const float* x  = (const float*)d_in[0];
    const float* v  = (const float*)d_in[1];
    const float* W1 = (const float*)d_in[2];
    const float* b1 = (const float*)d_in[3];
    const float* W2 = (const float*)d_in[4];
    const float* b2 = (const float*)d_in[5];
    const float* W3 = (const float*)d_in[6];
    const float* b3 = (const float*)d_in[7];
    float* out = (float*)d_out;
    const int B = in_sizes[0] / DIMV;   // 65536

    auto al = [](size_t s) { return (s + 255) & ~(size_t)255; };
    auto need_for = [&](size_t C) {
        size_t s = 0;
        s += al(C * DIMV * 4);       // z
        s += al(C * 4);              // lp
        s += al(C * HIDV * 2) * 2;   // g3, u
        s += al(128 * 512 * 2) * 3 + al(512 * 512 * 2) * 2; // packed weights
        return s;
    };
    size_t C = 32768;
    while (C > 1024 && need_for(C) > ws_size) C >>= 1;
    if (need_for(C) > ws_size) return;  // cannot run safely in this workspace

    char* w = (char*)d_ws;
    auto alloc = [&](size_t bytes) { char* p = w; w += al(bytes); return p; };
    float* z    = (float*)alloc(C * DIMV * 4);
    float* lp   = (float*)alloc(C * 4);
    unsigned short* g3 = (unsigned short*)alloc(C * HIDV * 2);
    unsigned short* u  = (unsigned short*)alloc(C * HIDV * 2);
    unsigned short* W1zp  = (unsigned short*)alloc(128 * 512 * 2);
    unsigned short* W3p   = (unsigned short*)alloc(512 * 128 * 2);
    unsigned short* W3Tp  = (unsigned short*)alloc(128 * 512 * 2);
    unsigned short* W2p   = (unsigned short*)alloc(512 * 512 * 2);
    unsigned short* W2Tp  = (unsigned short*)alloc(512 * 512 * 2);

    auto pack = [&](const float* src, unsigned short* dst, int K, int N, int ld, int tr) {
        pack_kernel<<<dim3((K * N + 255) / 256), dim3(256), 0, stream>>>(src, dst, K, N, ld, tr);
    };
    pack(W1, W1zp,  128, 512, 512, 0);
    pack(W2, W2p,   512, 512, 512, 0);
    pack(W3, W3p,   512, 128, 128, 0);
    pack(W2, W2Tp,  512, 512, 512, 1);
    pack(W3, W3Tp,  128, 512, 128, 1);

    const int GM128 = (int)C / 128;
    const int GMF   = (int)C / ROWS;

    for (int c0 = 0; c0 < B; c0 += (int)C) {
        const float* xc = x + (size_t)c0 * DIMV;
        const float* vc = v + (size_t)c0 * DIMV;

        // g3 = v @ W3^T ; u = v @ W1z  (once per chunk)
        vg_k<<<dim3(GM128, 2), 256, 0, stream>>>(vc, W3Tp, g3);
        vg_k<<<dim3(GM128, 2), 256, 0, stream>>>(vc, W1zp, u);

        // full 32-step RK4 integration in one persistent dispatch
        OArgs q{};
        q.x = xc;
        q.W1zp = W1zp; q.W2p = W2p; q.W3p = W3p; q.W2Tp = W2Tp;
        q.g3 = g3; q.u = u;
        q.b1 = b1; q.w1t = W1 + 128 * 512; q.b2 = b2; q.b3 = b3;
        q.z = z; q.lp = lp;
        ode_k<<<dim3(GMF), 512, 0, stream>>>(q);

        final_k<<<dim3((int)C / 16), 256, 0, stream>>>(z, lp, out + c0);
    }
}